// Round 1
// baseline (369.074 us; speedup 1.0000x reference)
//
#include <hip/hip_runtime.h>
#include <hip/hip_bf16.h>

typedef unsigned short u16;
typedef __bf16 bf16x8 __attribute__((ext_vector_type(8)));
typedef float f32x4 __attribute__((ext_vector_type(4)));
typedef unsigned short u16x8 __attribute__((ext_vector_type(8)));

// ---------- helpers ----------
__device__ __forceinline__ void async_copy16(void* lds, const void* g) {
  __builtin_amdgcn_global_load_lds(
      (const __attribute__((address_space(1))) unsigned int*)g,
      (__attribute__((address_space(3))) unsigned int*)lds, 16, 0, 0);
}

__device__ __forceinline__ u16 f2bf(float f) {
  __hip_bfloat16 h = __float2bfloat16(f);
  u16 u;
  __builtin_memcpy(&u, &h, 2);
  return u;
}

// ---------- f32 -> bf16 convert (vectorized) ----------
__global__ void k_f32_to_bf16(const float* __restrict__ in, u16* __restrict__ out, int n4) {
  int i = blockIdx.x * blockDim.x + threadIdx.x;
  if (i >= n4) return;
  float4 v = ((const float4*)in)[i];
  ushort4 o;
  o.x = f2bf(v.x); o.y = f2bf(v.y); o.z = f2bf(v.z); o.w = f2bf(v.w);
  ((ushort4*)out)[i] = o;
}

// ---------- transpose RxC f32 -> CxR bf16 ----------
__global__ void k_transpose_bf16(const float* __restrict__ in, u16* __restrict__ out, int R, int C) {
  __shared__ float tile[32][33];
  int bx = blockIdx.x * 32;  // col base (C)
  int by = blockIdx.y * 32;  // row base (R)
  int tx = threadIdx.x & 31, ty = threadIdx.x >> 5;  // 32 x 8
  for (int i = ty; i < 32; i += 8) tile[i][tx] = in[(size_t)(by + i) * C + bx + tx];
  __syncthreads();
  for (int i = ty; i < 32; i += 8) out[(size_t)(bx + i) * R + by + tx] = f2bf(tile[tx][i]);
}

// ---------- GEMM: C(MxN) = A(MxK,bf16) @ Bt(NxK,bf16)^T + bias ----------
// m97 structure: 128x128 tile, BK=32, 4 waves 2x2, global_load_lds w16,
// XOR swizzle phi(row)=(row>>1)&3 on 16B slots (linear dest + pre-swizzled src + swizzled read).
template <int OUT_BF16>
__global__ __launch_bounds__(256, 2) void k_gemm_bt(
    const u16* __restrict__ A, const u16* __restrict__ Bt,
    const float* __restrict__ bias, void* __restrict__ Cout,
    int M, int N, int K) {
  __shared__ __align__(16) u16 As[128][32];
  __shared__ __align__(16) u16 Bs[128][32];
  const int t = threadIdx.x;
  const int l = t & 63, w = t >> 6;
  const int lr = l & 15, lk = l >> 4;
  const int wr = w >> 1, wc = w & 1;
  const int m0 = blockIdx.x * 128, n0 = blockIdx.y * 128;

  f32x4 acc[4][4] = {};

  for (int k0 = 0; k0 < K; k0 += 32) {
    __syncthreads();
    for (int c = 0; c < 2; ++c) {
      int idx = c * 256 + t;
      int row = idx >> 2, slot = idx & 3;
      int sw = (slot ^ ((row >> 1) & 3)) << 3;  // pre-swizzled source granule
      async_copy16((char*)&As[0][0] + idx * 16, A + (size_t)(m0 + row) * K + k0 + sw);
      async_copy16((char*)&Bs[0][0] + idx * 16, Bt + (size_t)(n0 + row) * K + k0 + sw);
    }
    __syncthreads();
    bf16x8 af[4], bfr[4];
    for (int m = 0; m < 4; ++m) {
      int row = wr * 64 + m * 16 + lr;
      af[m] = *(const bf16x8*)((const char*)&As[0][0] + row * 64 + ((lk ^ ((row >> 1) & 3)) << 4));
    }
    for (int n = 0; n < 4; ++n) {
      int row = wc * 64 + n * 16 + lr;
      bfr[n] = *(const bf16x8*)((const char*)&Bs[0][0] + row * 64 + ((lk ^ ((row >> 1) & 3)) << 4));
    }
    for (int m = 0; m < 4; ++m)
      for (int n = 0; n < 4; ++n)
        acc[m][n] = __builtin_amdgcn_mfma_f32_16x16x32_bf16(af[m], bfr[n], acc[m][n], 0, 0, 0);
  }

  for (int n = 0; n < 4; ++n) {
    int col = n0 + wc * 64 + n * 16 + lr;
    float bv = bias[col];
    for (int m = 0; m < 4; ++m) {
      int rowb = m0 + wr * 64 + m * 16 + lk * 4;
      for (int r = 0; r < 4; ++r) {
        float v = acc[m][n][r] + bv;
        size_t off = (size_t)(rowb + r) * N + col;
        if constexpr (OUT_BF16) ((u16*)Cout)[off] = f2bf(v);
        else ((float*)Cout)[off] = v;
      }
    }
  }
}

// ---------- flash attention, causal, bf16 ----------
// grid (S/128, B*H); block 256 = 4 waves x 32 q-rows; KV tiles of 64.
__global__ __launch_bounds__(256, 2) void k_attn(
    const u16* __restrict__ QKV,  // (B*S) x 3072 bf16: [Q|K|V]
    u16* __restrict__ O) {        // (B*S) x 1024 bf16
  const int qt = blockIdx.x;  // 0..15
  const int bh = blockIdx.y;  // 0..63
  const int b = bh >> 4, h = bh & 15;
  const int t = threadIdx.x;
  const int l = t & 63, w = t >> 6;
  const int lr = l & 15, lk = l >> 4;

  __shared__ __align__(16) u16 Ks[64][64];     // key tile, row=k idx, col=dh (src-swizzled)
  __shared__ __align__(16) u16 VT[64][64];     // V transposed [dh][k], two-sided swizzle
  __shared__ __align__(16) u16 Pl[4][32][72];  // per-wave P transpose buffer (+8 pad)

  const int q0 = qt * 128 + w * 32;
  const size_t rowQ = (size_t)b * 2048 + q0;

  // Q fragments in registers (row = q0+m*16+lr, k-chunk c)
  bf16x8 qf[2][2];
  for (int m = 0; m < 2; ++m)
    for (int c = 0; c < 2; ++c)
      qf[m][c] = *(const bf16x8*)(QKV + (rowQ + m * 16 + lr) * 3072 + h * 64 + c * 32 + lk * 8);

  f32x4 acc_o[2][4] = {};
  float mi[2][4], li[2][4];
  for (int m = 0; m < 2; ++m)
    for (int r = 0; r < 4; ++r) { mi[m][r] = -__builtin_inff(); li[m][r] = 0.f; }

  const int qmax = q0 + 31;
  const int ntiles = 2 * qt + 2;
  const int diagj = 2 * qt;

  for (int j = 0; j < ntiles; ++j) {
    __syncthreads();  // previous tile's LDS reads done before overwrite
    {
      const u16* Kb = QKV + ((size_t)b * 2048 + j * 64) * 3072 + 1024 + h * 64;
      const u16* Vb = Kb + 1024;
      for (int c = 0; c < 2; ++c) {  // K: global_load_lds, source pre-swizzled by (row&7)
        int gi = c * 256 + t;
        int row = gi >> 3, slot = gi & 7;
        async_copy16((char*)&Ks[0][0] + gi * 16, Kb + (size_t)row * 3072 + ((slot ^ (row & 7)) << 3));
      }
      for (int c = 0; c < 2; ++c) {  // V: reg-staged transpose, phi(dh)=(dh&7)^((dh>>3)&7)
        int gi = c * 256 + t;
        int r = gi >> 3, dh0 = (gi & 7) << 3;
        u16x8 v = *(const u16x8*)(Vb + (size_t)r * 3072 + dh0);
        for (int jj = 0; jj < 8; ++jj) {
          int dh = dh0 + jj;
          int phi = (dh & 7) ^ ((dh >> 3) & 7);
          VT[dh][((((r >> 3) ^ phi) & 7) << 3) | (r & 7)] = v[jj];
        }
      }
    }
    __syncthreads();

    const bool active = (j * 64 <= qmax);
    if (active) {
      // ---- S = Q @ K^T ----
      f32x4 s[2][4] = {};
      for (int c = 0; c < 2; ++c)
        for (int n = 0; n < 4; ++n) {
          int row = n * 16 + lr;
          bf16x8 kf = *(const bf16x8*)((const char*)&Ks[0][0] + row * 128 +
                                       ((((c * 4 + lk) ^ (row & 7)) & 7) << 4));
          s[0][n] = __builtin_amdgcn_mfma_f32_16x16x32_bf16(qf[0][c], kf, s[0][n], 0, 0, 0);
          s[1][n] = __builtin_amdgcn_mfma_f32_16x16x32_bf16(qf[1][c], kf, s[1][n], 0, 0, 0);
        }
      // ---- scale + causal mask ----
      const bool needmask = (j >= diagj);
      for (int m = 0; m < 2; ++m)
        for (int n = 0; n < 4; ++n)
          for (int r = 0; r < 4; ++r) {
            float v = s[m][n][r] * 0.125f;
            if (needmask) {
              int kidx = j * 64 + n * 16 + lr;
              int qidx = q0 + m * 16 + lk * 4 + r;
              if (kidx > qidx) v = -__builtin_inff();
            }
            s[m][n][r] = v;
          }
      // ---- online softmax (rows live in 16-lane lr groups) ----
      for (int m = 0; m < 2; ++m)
        for (int r = 0; r < 4; ++r) {
          float tm = fmaxf(fmaxf(s[m][0][r], s[m][1][r]), fmaxf(s[m][2][r], s[m][3][r]));
          tm = fmaxf(tm, __shfl_xor(tm, 1));
          tm = fmaxf(tm, __shfl_xor(tm, 2));
          tm = fmaxf(tm, __shfl_xor(tm, 4));
          tm = fmaxf(tm, __shfl_xor(tm, 8));
          float mnew = fmaxf(mi[m][r], tm);
          float alpha = __expf(mi[m][r] - mnew);
          mi[m][r] = mnew;
          li[m][r] *= alpha;
          for (int n = 0; n < 4; ++n) acc_o[m][n][r] *= alpha;
          float psum = 0.f;
          for (int n = 0; n < 4; ++n) {
            float p = __expf(s[m][n][r] - mnew);
            s[m][n][r] = p;
            psum += p;
          }
          psum += __shfl_xor(psum, 1);
          psum += __shfl_xor(psum, 2);
          psum += __shfl_xor(psum, 4);
          psum += __shfl_xor(psum, 8);
          li[m][r] += psum;
        }
      // ---- P -> LDS (transpose to A-fragment layout) ----
      for (int m = 0; m < 2; ++m)
        for (int n = 0; n < 4; ++n)
          for (int r = 0; r < 4; ++r)
            Pl[w][m * 16 + lk * 4 + r][n * 16 + lr] = f2bf(s[m][n][r]);
      // ---- O += P @ V ---- (same-wave write->read ordered by lgkmcnt)
      for (int c = 0; c < 2; ++c) {
        bf16x8 pa0 = *(const bf16x8*)&Pl[w][lr][c * 32 + lk * 8];
        bf16x8 pa1 = *(const bf16x8*)&Pl[w][16 + lr][c * 32 + lk * 8];
        for (int n = 0; n < 4; ++n) {
          int dh = n * 16 + lr;
          int phi = (dh & 7) ^ ((dh >> 3) & 7);
          bf16x8 vf = *(const bf16x8*)((const char*)&VT[0][0] + dh * 128 +
                                       ((((c * 4 + lk) ^ phi) & 7) << 4));
          acc_o[0][n] = __builtin_amdgcn_mfma_f32_16x16x32_bf16(pa0, vf, acc_o[0][n], 0, 0, 0);
          acc_o[1][n] = __builtin_amdgcn_mfma_f32_16x16x32_bf16(pa1, vf, acc_o[1][n], 0, 0, 0);
        }
      }
    }
  }
  // ---- epilogue: O = acc / l ----
  for (int m = 0; m < 2; ++m)
    for (int r = 0; r < 4; ++r) {
      float inv = 1.0f / li[m][r];
      size_t orow = (rowQ + m * 16 + lk * 4 + r) * 1024 + h * 64;
      for (int n = 0; n < 4; ++n) O[orow + n * 16 + lr] = f2bf(acc_o[m][n][r] * inv);
    }
}

// ---------- launch ----------
extern "C" void kernel_launch(void* const* d_in, const int* in_sizes, int n_in,
                              void* d_out, int out_size, void* d_ws, size_t ws_size,
                              hipStream_t stream) {
  const float* x = (const float*)d_in[0];
  const float* w_qkv = (const float*)d_in[1];
  const float* b_qkv = (const float*)d_in[2];
  const float* w_out = (const float*)d_in[3];
  const float* b_out = (const float*)d_in[4];
  // d_in[5] = mask: always causal tril, handled analytically.

  char* ws = (char*)d_ws;
  u16* X16 = (u16*)(ws);                  // 16 MB (B*S x D bf16); reused as O16 after GEMM1
  u16* WqkvT = (u16*)(ws + 16777216);     // 6 MB  (3072 x 1024 bf16)
  u16* WoutT = (u16*)(ws + 23068672);     // 2 MB  (1024 x 1024 bf16)
  u16* QKVb = (u16*)(ws + 25165824);      // 48 MB (B*S x 3072 bf16)
  u16* O16 = X16;

  k_f32_to_bf16<<<8192, 256, 0, stream>>>(x, X16, 8388608 / 4);
  k_transpose_bf16<<<dim3(96, 32), 256, 0, stream>>>(w_qkv, WqkvT, 1024, 3072);
  k_transpose_bf16<<<dim3(32, 32), 256, 0, stream>>>(w_out, WoutT, 1024, 1024);
  k_gemm_bt<1><<<dim3(64, 24), 256, 0, stream>>>(X16, WqkvT, b_qkv, QKVb, 8192, 3072, 1024);
  k_attn<<<dim3(16, 64), 256, 0, stream>>>(QKVb, O16);
  k_gemm_bt<0><<<dim3(64, 8), 256, 0, stream>>>(O16, WoutT, b_out, d_out, 8192, 1024, 1024);
}

// Round 2
// 270.025 us; speedup vs baseline: 1.3668x; 1.3668x over previous
//
#include <hip/hip_runtime.h>
#include <hip/hip_bf16.h>

typedef unsigned short u16;
typedef __bf16 bf16x8 __attribute__((ext_vector_type(8)));
typedef float f32x4 __attribute__((ext_vector_type(4)));
typedef unsigned short u16x8 __attribute__((ext_vector_type(8)));

// ---------- helpers ----------
__device__ __forceinline__ void async_copy16(void* lds, const void* g) {
  __builtin_amdgcn_global_load_lds(
      (const __attribute__((address_space(1))) unsigned int*)g,
      (__attribute__((address_space(3))) unsigned int*)lds, 16, 0, 0);
}

__device__ __forceinline__ u16 f2bf(float f) {
  __hip_bfloat16 h = __float2bfloat16(f);
  u16 u;
  __builtin_memcpy(&u, &h, 2);
  return u;
}

// ---------- f32 -> bf16 convert (vectorized) ----------
__global__ void k_f32_to_bf16(const float* __restrict__ in, u16* __restrict__ out, int n4) {
  int i = blockIdx.x * blockDim.x + threadIdx.x;
  if (i >= n4) return;
  float4 v = ((const float4*)in)[i];
  ushort4 o;
  o.x = f2bf(v.x); o.y = f2bf(v.y); o.z = f2bf(v.z); o.w = f2bf(v.w);
  ((ushort4*)out)[i] = o;
}

// ---------- transpose RxC f32 -> CxR bf16 ----------
__global__ void k_transpose_bf16(const float* __restrict__ in, u16* __restrict__ out, int R, int C) {
  __shared__ float tile[32][33];
  int bx = blockIdx.x * 32;
  int by = blockIdx.y * 32;
  int tx = threadIdx.x & 31, ty = threadIdx.x >> 5;
  for (int i = ty; i < 32; i += 8) tile[i][tx] = in[(size_t)(by + i) * C + bx + tx];
  __syncthreads();
  for (int i = ty; i < 32; i += 8) out[(size_t)(bx + i) * R + by + tx] = f2bf(tile[tx][i]);
}

// ---------- GEMM: C(MxN) = A(MxK,bf16) @ Bt(NxK,bf16)^T + bias ----------
template <int OUT_BF16>
__global__ __launch_bounds__(256, 2) void k_gemm_bt(
    const u16* __restrict__ A, const u16* __restrict__ Bt,
    const float* __restrict__ bias, void* __restrict__ Cout,
    int M, int N, int K) {
  __shared__ __align__(16) u16 As[128][32];
  __shared__ __align__(16) u16 Bs[128][32];
  const int t = threadIdx.x;
  const int l = t & 63, w = t >> 6;
  const int lr = l & 15, lk = l >> 4;
  const int wr = w >> 1, wc = w & 1;
  const int m0 = blockIdx.x * 128, n0 = blockIdx.y * 128;

  f32x4 acc[4][4] = {};

  for (int k0 = 0; k0 < K; k0 += 32) {
    __syncthreads();
    for (int c = 0; c < 2; ++c) {
      int idx = c * 256 + t;
      int row = idx >> 2, slot = idx & 3;
      int sw = (slot ^ ((row >> 1) & 3)) << 3;
      async_copy16((char*)&As[0][0] + idx * 16, A + (size_t)(m0 + row) * K + k0 + sw);
      async_copy16((char*)&Bs[0][0] + idx * 16, Bt + (size_t)(n0 + row) * K + k0 + sw);
    }
    __syncthreads();
    bf16x8 af[4], bfr[4];
    for (int m = 0; m < 4; ++m) {
      int row = wr * 64 + m * 16 + lr;
      af[m] = *(const bf16x8*)((const char*)&As[0][0] + row * 64 + ((lk ^ ((row >> 1) & 3)) << 4));
    }
    for (int n = 0; n < 4; ++n) {
      int row = wc * 64 + n * 16 + lr;
      bfr[n] = *(const bf16x8*)((const char*)&Bs[0][0] + row * 64 + ((lk ^ ((row >> 1) & 3)) << 4));
    }
    for (int m = 0; m < 4; ++m)
      for (int n = 0; n < 4; ++n)
        acc[m][n] = __builtin_amdgcn_mfma_f32_16x16x32_bf16(af[m], bfr[n], acc[m][n], 0, 0, 0);
  }

  for (int n = 0; n < 4; ++n) {
    int col = n0 + wc * 64 + n * 16 + lr;
    float bv = bias[col];
    for (int m = 0; m < 4; ++m) {
      int rowb = m0 + wr * 64 + m * 16 + lk * 4;
      for (int r = 0; r < 4; ++r) {
        float v = acc[m][n][r] + bv;
        size_t off = (size_t)(rowb + r) * N + col;
        if constexpr (OUT_BF16) ((u16*)Cout)[off] = f2bf(v);
        else ((float*)Cout)[off] = v;
      }
    }
  }
}

// ---------- flash attention, causal, bf16, paired q-tiles ----------
// grid (8, B*H); block 256 = 4 waves. Block p handles q-tiles p (A, light)
// and 15-p (B, heavy) jointly over B's KV range -> exactly 34 tile-units per
// wave (perfect balance). KV double-buffered: global_load_lds K + reg-staged V
// issued before compute, V ds_write after, 1 barrier/tile.
__global__ __launch_bounds__(256, 2) void k_attn(
    const u16* __restrict__ QKV,  // (B*S) x 3072 bf16: [Q|K|V]
    u16* __restrict__ O) {        // (B*S) x 1024 bf16
  const int p = blockIdx.x;   // 0..7
  const int bh = blockIdx.y;  // 0..63
  const int b = bh >> 4, h = bh & 15;
  const int t = threadIdx.x;
  const int l = t & 63, w = t >> 6;
  const int lr = l & 15, lk = l >> 4;

  __shared__ __align__(16) u16 Ks[2][64][64];   // key tiles (src-swizzled), dbuf
  __shared__ __align__(16) u16 VT[2][64][64];   // V^T tiles (two-sided swizzle), dbuf
  __shared__ __align__(16) u16 Pl[4][64][72];   // per-wave P: rows 0-31 = A, 32-63 = B

  const int qtA = p, qtB = 15 - p;
  const int ntA = 2 * qtA + 2, ntB = 2 * qtB + 2;  // ntA + ntB = 34
  const int q0A = qtA * 128 + w * 32, q0B = qtB * 128 + w * 32;
  const size_t rowQA = (size_t)b * 2048 + q0A;
  const size_t rowQB = (size_t)b * 2048 + q0B;

  // Q fragments in registers
  bf16x8 qfA[2][2], qfB[2][2];
#pragma unroll
  for (int m = 0; m < 2; ++m)
#pragma unroll
    for (int c = 0; c < 2; ++c) {
      qfA[m][c] = *(const bf16x8*)(QKV + (rowQA + m * 16 + lr) * 3072 + h * 64 + c * 32 + lk * 8);
      qfB[m][c] = *(const bf16x8*)(QKV + (rowQB + m * 16 + lr) * 3072 + h * 64 + c * 32 + lk * 8);
    }

  f32x4 accA[2][4] = {}, accB[2][4] = {};
  float miA[2][4], liA[2][4], miB[2][4], liB[2][4];
#pragma unroll
  for (int m = 0; m < 2; ++m)
#pragma unroll
    for (int r = 0; r < 4; ++r) {
      miA[m][r] = -__builtin_inff(); liA[m][r] = 0.f;
      miB[m][r] = -__builtin_inff(); liB[m][r] = 0.f;
    }

  const u16* Kb0 = QKV + (size_t)b * 2048 * 3072 + 1024 + h * 64;
  const u16* Vb0 = Kb0 + 1024;

  u16x8 vreg[2];

  auto stageK = [&](int j, int buf) {
#pragma unroll
    for (int c = 0; c < 2; ++c) {
      int gi = c * 256 + t;
      int row = gi >> 3, slot = gi & 7;
      async_copy16((char*)&Ks[buf][0][0] + gi * 16,
                   Kb0 + ((size_t)j * 64 + row) * 3072 + ((slot ^ (row & 7)) << 3));
    }
  };
  auto loadV = [&](int j) {
#pragma unroll
    for (int c = 0; c < 2; ++c) {
      int r = c * 32 + (t >> 3), dh0 = (t & 7) << 3;
      vreg[c] = *(const u16x8*)(Vb0 + ((size_t)j * 64 + r) * 3072 + dh0);
    }
  };
  auto writeV = [&](int buf) {
#pragma unroll
    for (int c = 0; c < 2; ++c) {
      int r = c * 32 + (t >> 3), dh0 = (t & 7) << 3;
#pragma unroll
      for (int jj = 0; jj < 8; ++jj) {
        int dh = dh0 + jj;
        int phi = (dh & 7) ^ ((dh >> 3) & 7);
        VT[buf][dh][((((r >> 3) ^ phi) & 7) << 3) | (r & 7)] = vreg[c][jj];
      }
    }
  };

  // QK^T + online softmax + P->LDS for one q-tile
  auto qk_sm = [&](const bf16x8 (*qf)[2], float (*mi)[4], float (*li)[4], f32x4 (*acc)[4],
                   int q0w, int plbase, int j, int cur) {
    f32x4 s[2][4] = {};
#pragma unroll
    for (int c = 0; c < 2; ++c)
#pragma unroll
      for (int n = 0; n < 4; ++n) {
        int row = n * 16 + lr;
        bf16x8 kf = *(const bf16x8*)((const char*)&Ks[cur][0][0] + row * 128 +
                                     ((((c * 4 + lk) ^ (row & 7)) & 7) << 4));
        s[0][n] = __builtin_amdgcn_mfma_f32_16x16x32_bf16(qf[0][c], kf, s[0][n], 0, 0, 0);
        s[1][n] = __builtin_amdgcn_mfma_f32_16x16x32_bf16(qf[1][c], kf, s[1][n], 0, 0, 0);
      }
    const bool needmask = (j * 64 + 63 > q0w);
#pragma unroll
    for (int m = 0; m < 2; ++m)
#pragma unroll
      for (int n = 0; n < 4; ++n)
#pragma unroll
        for (int r = 0; r < 4; ++r) {
          float v = s[m][n][r] * 0.125f;
          if (needmask && (j * 64 + n * 16 + lr > q0w + m * 16 + lk * 4 + r))
            v = -__builtin_inff();
          s[m][n][r] = v;
        }
    float tm[2][4];
#pragma unroll
    for (int m = 0; m < 2; ++m)
#pragma unroll
      for (int r = 0; r < 4; ++r) {
        float x = fmaxf(fmaxf(s[m][0][r], s[m][1][r]), fmaxf(s[m][2][r], s[m][3][r]));
        x = fmaxf(x, __shfl_xor(x, 1));
        x = fmaxf(x, __shfl_xor(x, 2));
        x = fmaxf(x, __shfl_xor(x, 4));
        x = fmaxf(x, __shfl_xor(x, 8));
        tm[m][r] = x;
      }
    // defer-max (T13): only rescale when max grew by > 8
    bool need = false;
#pragma unroll
    for (int m = 0; m < 2; ++m)
#pragma unroll
      for (int r = 0; r < 4; ++r) need |= (tm[m][r] > mi[m][r] + 8.0f);
    if (__any(need)) {
#pragma unroll
      for (int m = 0; m < 2; ++m)
#pragma unroll
        for (int r = 0; r < 4; ++r) {
          float mnew = fmaxf(mi[m][r], tm[m][r]);
          float alpha = __expf(mi[m][r] - mnew);
          mi[m][r] = mnew;
          li[m][r] *= alpha;
#pragma unroll
          for (int n = 0; n < 4; ++n) acc[m][n][r] *= alpha;
        }
    }
#pragma unroll
    for (int m = 0; m < 2; ++m)
#pragma unroll
      for (int r = 0; r < 4; ++r) {
        float ps = 0.f;
#pragma unroll
        for (int n = 0; n < 4; ++n) {
          float pv = __expf(s[m][n][r] - mi[m][r]);
          ps += pv;
          Pl[w][plbase + m * 16 + lk * 4 + r][n * 16 + lr] = f2bf(pv);
        }
        ps += __shfl_xor(ps, 1);
        ps += __shfl_xor(ps, 2);
        ps += __shfl_xor(ps, 4);
        ps += __shfl_xor(ps, 8);
        li[m][r] += ps;
      }
  };

  // prologue: tile 0 into buffer 0
  stageK(0, 0);
  loadV(0);
  writeV(0);
  __syncthreads();

  for (int j = 0; j < ntB; ++j) {
    const int cur = j & 1;
    const bool more = (j + 1 < ntB);
    if (more) { stageK(j + 1, cur ^ 1); loadV(j + 1); }  // in flight during compute
    const bool doA = (j < ntA);

    qk_sm(qfB, miB, liB, accB, q0B, 32, j, cur);
    if (doA) qk_sm(qfA, miA, liA, accA, q0A, 0, j, cur);

    // ---- O += P @ V (V fragments shared between A and B) ----
#pragma unroll
    for (int c = 0; c < 2; ++c) {
      bf16x8 paB0 = *(const bf16x8*)&Pl[w][32 + lr][c * 32 + lk * 8];
      bf16x8 paB1 = *(const bf16x8*)&Pl[w][48 + lr][c * 32 + lk * 8];
      bf16x8 paA0 = {}, paA1 = {};
      if (doA) {
        paA0 = *(const bf16x8*)&Pl[w][lr][c * 32 + lk * 8];
        paA1 = *(const bf16x8*)&Pl[w][16 + lr][c * 32 + lk * 8];
      }
#pragma unroll
      for (int n = 0; n < 4; ++n) {
        int dh = n * 16 + lr;
        int phi = (dh & 7) ^ ((dh >> 3) & 7);
        bf16x8 vf = *(const bf16x8*)((const char*)&VT[cur][0][0] + dh * 128 +
                                     ((((c * 4 + lk) ^ phi) & 7) << 4));
        accB[0][n] = __builtin_amdgcn_mfma_f32_16x16x32_bf16(paB0, vf, accB[0][n], 0, 0, 0);
        accB[1][n] = __builtin_amdgcn_mfma_f32_16x16x32_bf16(paB1, vf, accB[1][n], 0, 0, 0);
        if (doA) {
          accA[0][n] = __builtin_amdgcn_mfma_f32_16x16x32_bf16(paA0, vf, accA[0][n], 0, 0, 0);
          accA[1][n] = __builtin_amdgcn_mfma_f32_16x16x32_bf16(paA1, vf, accA[1][n], 0, 0, 0);
        }
      }
    }

    if (more) writeV(cur ^ 1);  // V regs -> other buffer (vmcnt waited by compiler)
    __syncthreads();            // drains global_load_lds (vmcnt) + LDS writes
  }

  // ---- epilogue: O = acc / l ----
#pragma unroll
  for (int m = 0; m < 2; ++m)
#pragma unroll
    for (int r = 0; r < 4; ++r) {
      float invB = 1.0f / liB[m][r];
      size_t orowB = (rowQB + m * 16 + lk * 4 + r) * 1024 + h * 64;
#pragma unroll
      for (int n = 0; n < 4; ++n) O[orowB + n * 16 + lr] = f2bf(accB[m][n][r] * invB);
      float invA = 1.0f / liA[m][r];
      size_t orowA = (rowQA + m * 16 + lk * 4 + r) * 1024 + h * 64;
#pragma unroll
      for (int n = 0; n < 4; ++n) O[orowA + n * 16 + lr] = f2bf(accA[m][n][r] * invA);
    }
}

// ---------- launch ----------
extern "C" void kernel_launch(void* const* d_in, const int* in_sizes, int n_in,
                              void* d_out, int out_size, void* d_ws, size_t ws_size,
                              hipStream_t stream) {
  const float* x = (const float*)d_in[0];
  const float* w_qkv = (const float*)d_in[1];
  const float* b_qkv = (const float*)d_in[2];
  const float* w_out = (const float*)d_in[3];
  const float* b_out = (const float*)d_in[4];
  // d_in[5] = mask: always causal tril, handled analytically.

  char* ws = (char*)d_ws;
  u16* X16 = (u16*)(ws);                  // 16 MB; reused as O16 after GEMM1
  u16* WqkvT = (u16*)(ws + 16777216);     // 6 MB
  u16* WoutT = (u16*)(ws + 23068672);     // 2 MB
  u16* QKVb = (u16*)(ws + 25165824);      // 48 MB
  u16* O16 = X16;

  k_f32_to_bf16<<<8192, 256, 0, stream>>>(x, X16, 8388608 / 4);
  k_transpose_bf16<<<dim3(96, 32), 256, 0, stream>>>(w_qkv, WqkvT, 1024, 3072);
  k_transpose_bf16<<<dim3(32, 32), 256, 0, stream>>>(w_out, WoutT, 1024, 1024);
  k_gemm_bt<1><<<dim3(64, 24), 256, 0, stream>>>(X16, WqkvT, b_qkv, QKVb, 8192, 3072, 1024);
  k_attn<<<dim3(8, 64), 256, 0, stream>>>(QKVb, O16);
  k_gemm_bt<0><<<dim3(64, 8), 256, 0, stream>>>(O16, WoutT, b_out, d_out, 8192, 1024, 1024);
}